// Round 16
// baseline (345.124 us; speedup 1.0000x reference)
//
#include <hip/hip_runtime.h>
#include <stdint.h>

// ---------------- problem constants (b=1, f=8, h=16, w=32) ----------------
#define S_TOK 4096
#define DIM   2304
#define NH    24
#define DH    96
#define GQ    1024     // sparse sequence length (4096/4)
#define KDIM  2304

typedef unsigned short ushort_t;
typedef __attribute__((ext_vector_type(8))) short bf16x8;   // 8 bf16 = 4 VGPRs
typedef __attribute__((ext_vector_type(4))) float f32x4;

__device__ __forceinline__ ushort_t f2bf(float x) {
    union { float f; uint32_t u; } c; c.f = x;
    uint32_t u = c.u + 0x7FFFu + ((c.u >> 16) & 1u);   // RNE
    return (ushort_t)(u >> 16);
}

#define GLDS(gp, lp) __builtin_amdgcn_global_load_lds( \
    (const __attribute__((address_space(1))) void*)(gp), \
    (__attribute__((address_space(3))) void*)(lp), 16, 0, 0)

// ---------------- elementwise cast fp32 -> bf16 ----------------
__global__ __launch_bounds__(256) void cast_bf16_kernel(const float* __restrict__ in,
                                                        ushort_t* __restrict__ out, int n4) {
    int i = blockIdx.x * 256 + threadIdx.x;
    if (i >= n4) return;
    float4 v = ((const float4*)in)[i];
    ushort4 o;
    o.x = f2bf(v.x); o.y = f2bf(v.y); o.z = f2bf(v.z); o.w = f2bf(v.w);
    ((ushort4*)out)[i] = o;
}

// ---- W [k][n] fp32 -> WT [n][k] bf16, all 4 weights in one launch (z = which) ----
__global__ __launch_bounds__(256) void wtrans_kernel(const float* __restrict__ W0,
                                                     const float* __restrict__ W1,
                                                     const float* __restrict__ W2,
                                                     const float* __restrict__ W3,
                                                     ushort_t* __restrict__ WT0, int dim) {
    __shared__ float tile[32][33];
    const int z = blockIdx.z;
    const float* W = (z == 0) ? W0 : (z == 1) ? W1 : (z == 2) ? W2 : W3;
    ushort_t* WT = WT0 + (size_t)z * dim * dim;
    const int bx = blockIdx.x * 32;   // n block
    const int by = blockIdx.y * 32;   // k block
    const int tx = threadIdx.x & 31, ty = threadIdx.x >> 5;
#pragma unroll
    for (int i = 0; i < 4; ++i)
        tile[ty + i*8][tx] = W[(size_t)(by + ty + i*8) * dim + bx + tx];
    __syncthreads();
#pragma unroll
    for (int i = 0; i < 4; ++i)
        WT[(size_t)(bx + ty + i*8) * dim + by + tx] = f2bf(tile[tx][ty + i*8]);
}

// ---------------- 128x128 QKV GEMM: 4 blocks/CU, 1728 blocks ----------------------
// Conflict-free gemm128 structure applied to the QKV projection (N = 6912).
// 2-slot double buffer (32 KB LDS), counted vmcnt(4), XOR swizzle pair.
// mode = bx/18: 0 = Q (rope, exp2-fold scale), 1 = K (rope), 2 = V^T scatter.
__global__ __launch_bounds__(256, 4) void gemm128_qkv(const ushort_t* __restrict__ A,
                                                      const ushort_t* __restrict__ Bt,
                                                      const float* __restrict__ bq,
                                                      const float* __restrict__ bk,
                                                      const float* __restrict__ bv,
                                                      ushort_t* __restrict__ Qb,
                                                      ushort_t* __restrict__ Kb,
                                                      ushort_t* __restrict__ Vtb) {
    constexpr int K  = KDIM;
    constexpr int NT = K / 32;                 // 72 K-tiles
    __shared__ ushort_t a_s[2 * 4096];         // 2 slots x [128][32] bf16 = 16 KB
    __shared__ ushort_t b_s[2 * 4096];
    const int t = threadIdx.x;
    const int l = t & 63, w = t >> 6;
    const int wr = w >> 1, wc = w & 1;
    const int g = l >> 4, ln = l & 15;
    // grid (54,32) = 1728 blocks; bijective XCD swizzle (1728 % 8 == 0)
    const int lin = blockIdx.y * gridDim.x + blockIdx.x;
    const int swz = (lin & 7) * 216 + (lin >> 3);
    const int bx = swz % 54, by = swz / 54;
    const int m0 = by * 128, n0g = bx * 128;   // n0g = global output column

    const int swz_rd = (g ^ ((ln >> 1) & 3)) * 8;            // read-side swizzle
    const int kc_src = (((t & 3) ^ ((t >> 3) & 3)) * 8);     // stage-side inverse
    const int srow   = t >> 2;                                // 0..63

    const ushort_t* Ab = A  + (size_t)(m0  + srow) * K + kc_src;
    const ushort_t* Bb = Bt + (size_t)(n0g + srow) * K + kc_src;
    const size_t rstep = (size_t)64 * K;

    auto stage = [&](int kt) {
        const int slot = kt & 1;
        GLDS(Ab + kt*32,         &a_s[slot*4096 + t*8]);
        GLDS(Ab + rstep + kt*32, &a_s[slot*4096 + 2048 + t*8]);
        GLDS(Bb + kt*32,         &b_s[slot*4096 + t*8]);
        GLDS(Bb + rstep + kt*32, &b_s[slot*4096 + 2048 + t*8]);
    };

    f32x4 acc[4][4] = {};

    stage(0); stage(1);
    asm volatile("s_waitcnt vmcnt(4)" ::: "memory");   // tile 0 landed (own lanes)
    __builtin_amdgcn_s_barrier();                      // -> landed for all waves

    for (int kt = 0; kt < NT; ++kt) {
        const int slot = kt & 1;
        bf16x8 av[4], bv4[4];
#pragma unroll
        for (int i = 0; i < 4; ++i)
            av[i] = *(const bf16x8*)&a_s[slot*4096 + (wr*64 + i*16 + ln) * 32 + swz_rd];
#pragma unroll
        for (int j = 0; j < 4; ++j)
            bv4[j] = *(const bf16x8*)&b_s[slot*4096 + (wc*64 + j*16 + ln) * 32 + swz_rd];
        asm volatile("s_waitcnt lgkmcnt(0)" ::: "memory");   // own reads of slot done
        __builtin_amdgcn_sched_barrier(0);
        __builtin_amdgcn_s_barrier();                        // ALL waves done with slot
        if (kt < NT - 2) {
            stage(kt + 2);                                   // overwrite slot safely
            asm volatile("s_waitcnt vmcnt(4)" ::: "memory"); // tile kt+1 landed
        } else {
            asm volatile("s_waitcnt vmcnt(0)" ::: "memory");
        }
        __builtin_amdgcn_sched_barrier(0);
        __builtin_amdgcn_s_setprio(1);
#pragma unroll
        for (int i = 0; i < 4; ++i)
#pragma unroll
            for (int j = 0; j < 4; ++j)
                acc[i][j] = __builtin_amdgcn_mfma_f32_16x16x32_bf16(av[i], bv4[j], acc[i][j], 0, 0, 0);
        __builtin_amdgcn_s_setprio(0);
        __builtin_amdgcn_sched_barrier(0);
        __builtin_amdgcn_s_barrier();      // all waves passed vmcnt -> next tile readable
    }

    const int mode = bx / 18;
    const int nb = (bx - mode * 18) * 128;     // local column within Q/K/V
    const float* bias = (mode == 0) ? bq : (mode == 1) ? bk : bv;
    if (mode == 2) {
        // V^T: [inst = r*24+h][d][q]
#pragma unroll
        for (int i = 0; i < 4; ++i) {
            int mb = m0 + wr*64 + i*16 + g*4;  // mb % 4 == 0
            int q  = mb >> 2;
#pragma unroll
            for (int j = 0; j < 4; ++j) {
                int nm = nb + wc*64 + j*16 + ln;
                int hh = nm / DH, d = nm - hh * DH;
                float bb = bias[nm];
#pragma unroll
                for (int r = 0; r < 4; ++r)
                    Vtb[(size_t)(r * NH + hh) * (DH * GQ) + (size_t)d * GQ + q] =
                        f2bf(acc[i][j][r] + bb);
            }
        }
    } else {
        ushort_t* O = (mode == 0) ? Qb : Kb;
        // Q scale folds 1/sqrt(96) AND log2(e): attn softmax runs in exp2 domain
        const float scq = (mode == 0) ? 0.1472444635222742f : 1.0f;
#pragma unroll
        for (int i = 0; i < 4; ++i) {
            int mb = m0 + wr*64 + i*16 + g*4;
#pragma unroll
            for (int jp = 0; jp < 2; ++jp) {
                int j  = jp * 2;
                int n1 = nb + wc*64 + j*16 + ln;   // even 16-tile -> d1%32 < 16
                int hh = n1 / DH, d1 = n1 - hh * DH;
                int sec = d1 >> 5, f = d1 & 15;
                float invf = __expf((float)f * -0.5756462732485114f);  // 10000^(-f/16)
                float b1 = bias[n1], b2 = bias[n1 + 16];
#pragma unroll
                for (int r = 0; r < 4; ++r) {
                    int m = mb + r;
                    int pos = (sec == 0) ? (m >> 9) : (sec == 1) ? ((m >> 5) & 15) : (m & 31);
                    float ang = (float)pos * invf;
                    float sn, cs;
                    __sincosf(ang, &sn, &cs);
                    float v1 = acc[i][j][r]     + b1;
                    float v2 = acc[i][j + 1][r] + b2;
                    size_t base = ((size_t)((m & 3) * NH + hh)) * (GQ * DH) + (size_t)(m >> 2) * DH;
                    O[base + d1]      = f2bf((v1 * cs - v2 * sn) * scq);
                    O[base + d1 + 16] = f2bf((v2 * cs + v1 * sn) * scq);
                }
            }
        }
    }
}

// ---------------- 128x128 GEMM (final projection), 2-slot double buffer ----------
__global__ __launch_bounds__(256) void gemm128(const ushort_t* __restrict__ A,
                                               const ushort_t* __restrict__ Bt,
                                               const float* __restrict__ bias,
                                               float* __restrict__ C) {
    constexpr int K  = KDIM;
    constexpr int NT = K / 32;                 // 72 K-tiles
    __shared__ ushort_t a_s[2 * 4096];         // 2 slots x [128][32] bf16 = 16 KB
    __shared__ ushort_t b_s[2 * 4096];
    const int t = threadIdx.x;
    const int l = t & 63, w = t >> 6;
    const int wr = w >> 1, wc = w & 1;
    const int g = l >> 4, ln = l & 15;
    // grid (18,32) = 576 blocks; bijective XCD swizzle (576 % 8 == 0)
    const int lin = blockIdx.y * gridDim.x + blockIdx.x;
    const int swz = (lin & 7) * 72 + (lin >> 3);
    const int bx = swz % 18, by = swz / 18;
    const int m0 = by * 128, n0 = bx * 128;

    const int swz_rd = (g ^ ((ln >> 1) & 3)) * 8;            // read-side swizzle
    const int kc_src = (((t & 3) ^ ((t >> 3) & 3)) * 8);     // stage-side inverse
    const int srow   = t >> 2;                                // 0..63

    const ushort_t* Ab = A  + (size_t)(m0 + srow) * K + kc_src;
    const ushort_t* Bb = Bt + (size_t)(n0 + srow) * K + kc_src;
    const size_t rstep = (size_t)64 * K;

    auto stage = [&](int kt) {
        const int slot = kt & 1;
        GLDS(Ab + kt*32,         &a_s[slot*4096 + t*8]);
        GLDS(Ab + rstep + kt*32, &a_s[slot*4096 + 2048 + t*8]);
        GLDS(Bb + kt*32,         &b_s[slot*4096 + t*8]);
        GLDS(Bb + rstep + kt*32, &b_s[slot*4096 + 2048 + t*8]);
    };

    f32x4 acc[4][4] = {};

    stage(0); stage(1);
    asm volatile("s_waitcnt vmcnt(4)" ::: "memory");   // tile 0 landed (own lanes)
    __builtin_amdgcn_s_barrier();                      // -> landed for all waves

    for (int kt = 0; kt < NT; ++kt) {
        const int slot = kt & 1;
        bf16x8 av[4], bv[4];
#pragma unroll
        for (int i = 0; i < 4; ++i)
            av[i] = *(const bf16x8*)&a_s[slot*4096 + (wr*64 + i*16 + ln) * 32 + swz_rd];
#pragma unroll
        for (int j = 0; j < 4; ++j)
            bv[j] = *(const bf16x8*)&b_s[slot*4096 + (wc*64 + j*16 + ln) * 32 + swz_rd];
        asm volatile("s_waitcnt lgkmcnt(0)" ::: "memory");   // own reads of slot done
        __builtin_amdgcn_sched_barrier(0);
        __builtin_amdgcn_s_barrier();                        // ALL waves done with slot
        if (kt < NT - 2) {
            stage(kt + 2);                                   // overwrite slot safely
            asm volatile("s_waitcnt vmcnt(4)" ::: "memory"); // tile kt+1 landed
        } else {
            asm volatile("s_waitcnt vmcnt(0)" ::: "memory");
        }
        __builtin_amdgcn_sched_barrier(0);
        __builtin_amdgcn_s_setprio(1);
#pragma unroll
        for (int i = 0; i < 4; ++i)
#pragma unroll
            for (int j = 0; j < 4; ++j)
                acc[i][j] = __builtin_amdgcn_mfma_f32_16x16x32_bf16(av[i], bv[j], acc[i][j], 0, 0, 0);
        __builtin_amdgcn_s_setprio(0);
        __builtin_amdgcn_sched_barrier(0);
        __builtin_amdgcn_s_barrier();      // all waves passed vmcnt -> next tile readable
    }

#pragma unroll
    for (int i = 0; i < 4; ++i) {
        int mb = m0 + wr*64 + i*16 + g*4;
#pragma unroll
        for (int j = 0; j < 4; ++j) {
            int n = n0 + wc*64 + j*16 + ln;
            float bb = bias[n];
#pragma unroll
            for (int r = 0; r < 4; ++r)
                C[(size_t)(mb + r) * DIM + n] = acc[i][j][r] + bb;
        }
    }
}

// ---------------- flash attention: 96 instances of [1024,96], V^T input ----------------
// R15 structure: exp2-domain softmax, exact defer-rescale, setprio clusters.
// 4 waves x 32 q-rows, KV tile 64, 52 KB LDS -> 3 blocks/CU.
__global__ __launch_bounds__(256, 3) void attn_kernel(const ushort_t* __restrict__ Qb,
                                                      const ushort_t* __restrict__ Kb,
                                                      const ushort_t* __restrict__ Vt,
                                                      ushort_t* __restrict__ ATT) {
    __shared__ ushort_t k_s[2][12 * 64 * 8];   // [buf][d-chunk][key][8]  24KB
    __shared__ ushort_t v_s[8 * 96 * 8];       // [key-chunk][d][8]       12KB
    __shared__ ushort_t p_s[4 * 2 * 16 * 64];  // [wave][qt][q16][key64]  16KB (XOR-swizzled)

    const int t = threadIdx.x, l = t & 63, w = t >> 6, g = l >> 4, ln = l & 15;
    // XCD-bijective swizzle: 768 blocks -> 96/XCD = 12 whole instances
    const int lin  = blockIdx.x;
    const int swz  = (lin & 7) * 96 + (lin >> 3);
    const int inst = swz >> 3;            // 0..95
    const int qb0  = (swz & 7) * 128;
    const int n_idx = inst / NH, h = inst - n_idx * NH;
    const int swzp = (ln & 7) << 3;       // P-LDS XOR swizzle (ushort units)

    const ushort_t* Qi = Qb + (size_t)inst * (GQ * DH);
    const ushort_t* Ki = Kb + (size_t)inst * (GQ * DH);
    const ushort_t* Vi = Vt + (size_t)inst * (DH * GQ);   // [96][1024]

    auto stageK = [&](int kt, int b) {
#pragma unroll
        for (int it = 0; it < 3; ++it) {
            int P = t + it * 256;              // 0..767 = [c<12][key<64]
            int c = P >> 6, key = P & 63;
            GLDS(Ki + (size_t)(kt * 64 + key) * DH + c * 8, &k_s[b][P * 8]);
        }
    };
    auto stageV = [&](int kt) {
#pragma unroll
        for (int it = 0; it < 3; ++it) {
            int P = t + it * 256;              // 0..767 = [c<8][d<96]
            int c = P / 96, d = P - c * 96;
            GLDS(Vi + (size_t)d * GQ + kt * 64 + c * 8, &v_s[P * 8]);
        }
    };

    // Q fragments (used as MFMA B-operand); Q carries log2e/sqrt(96)
    bf16x8 qf[2][3];
#pragma unroll
    for (int qt = 0; qt < 2; ++qt)
#pragma unroll
        for (int ks = 0; ks < 3; ++ks)
            qf[qt][ks] = *(const bf16x8*)(Qi + (size_t)(qb0 + w*32 + qt*16 + ln) * DH + ks*32 + g*8);

    float m_run[2], l_run[2];
#pragma unroll
    for (int qt = 0; qt < 2; ++qt) { m_run[qt] = -3.0e38f; l_run[qt] = 0.f; }
    f32x4 acc_o[2][6] = {};

    stageK(0, 0);
    stageV(0);
    __syncthreads();

    int cur = 0;
    for (int kt = 0; kt < 16; ++kt) {
        stageK((kt + 1) & 15, cur ^ 1);       // prefetch next K (3 GLDS in flight)
        float al2[2];
        bool grew[2];

        // S^T = K Q^T : lane holds q = ln, keys = ct*16 + g*4 + r  (exp2 domain)
        f32x4 sc[2][4] = {};
        __builtin_amdgcn_s_setprio(1);
#pragma unroll
        for (int ct = 0; ct < 4; ++ct) {
            bf16x8 kf0 = *(const bf16x8*)&k_s[cur][((0*4 + g)*64 + ct*16 + ln) * 8];
            bf16x8 kf1 = *(const bf16x8*)&k_s[cur][((1*4 + g)*64 + ct*16 + ln) * 8];
            bf16x8 kf2 = *(const bf16x8*)&k_s[cur][((2*4 + g)*64 + ct*16 + ln) * 8];
#pragma unroll
            for (int qi = 0; qi < 2; ++qi) {
                sc[qi][ct] = __builtin_amdgcn_mfma_f32_16x16x32_bf16(kf0, qf[qi][0], sc[qi][ct], 0, 0, 0);
                sc[qi][ct] = __builtin_amdgcn_mfma_f32_16x16x32_bf16(kf1, qf[qi][1], sc[qi][ct], 0, 0, 0);
                sc[qi][ct] = __builtin_amdgcn_mfma_f32_16x16x32_bf16(kf2, qf[qi][2], sc[qi][ct], 0, 0, 0);
            }
        }
        __builtin_amdgcn_s_setprio(0);
#pragma unroll
        for (int qi = 0; qi < 2; ++qi) {
            const int qt = qi;
            float mx = sc[qi][0][0];
#pragma unroll
            for (int ct = 0; ct < 4; ++ct)
#pragma unroll
                for (int r = 0; r < 4; ++r)
                    mx = fmaxf(mx, sc[qi][ct][r]);
            mx = fmaxf(mx, __shfl_xor(mx, 16, 64));
            mx = fmaxf(mx, __shfl_xor(mx, 32, 64));
            // exact defer: if no lane's max grew, keep m_run (P <= 1 still holds)
            bool grow = !__all(mx <= m_run[qt]);
            float al = 1.0f;
            if (grow) {
                float mn = fmaxf(m_run[qt], mx);
                al = __builtin_amdgcn_exp2f(m_run[qt] - mn);
                m_run[qt] = mn;
            }
            grew[qi] = grow;
            float rs = 0.f;
            ushort_t pb[16];
#pragma unroll
            for (int ct = 0; ct < 4; ++ct)
#pragma unroll
                for (int r = 0; r < 4; ++r) {
                    float p = __builtin_amdgcn_exp2f(sc[qi][ct][r] - m_run[qt]);
                    rs += p;
                    pb[ct*4 + r] = f2bf(p);
                }
            rs += __shfl_xor(rs, 16, 64);
            rs += __shfl_xor(rs, 32, 64);
            l_run[qt] = l_run[qt] * al + rs;
            al2[qt] = al;
            const int pbase = ((w*2 + qt)*16 + ln) * 64;
#pragma unroll
            for (int ct = 0; ct < 4; ++ct) {
                ushort4 pk;
                pk.x = pb[ct*4+0]; pk.y = pb[ct*4+1]; pk.z = pb[ct*4+2]; pk.w = pb[ct*4+3];
                *(ushort4*)&p_s[pbase + ((ct*16 + g*4) ^ swzp)] = pk;
            }
        }

        // rescale O by exp2(m_old - m_new) only when some row's max grew
        if (grew[0] || grew[1]) {
#pragma unroll
            for (int qt = 0; qt < 2; ++qt)
#pragma unroll
                for (int r = 0; r < 4; ++r) {
                    float a = __shfl(al2[qt], g*4 + r, 16);
#pragma unroll
                    for (int dt = 0; dt < 6; ++dt)
                        acc_o[qt][dt][r] *= a;
                }
        }

        // V(kt) landed (3 K-prefetch remain in flight); cross-wave visibility
        asm volatile("s_waitcnt vmcnt(3)" ::: "memory");
        __builtin_amdgcn_s_barrier();
        __builtin_amdgcn_sched_barrier(0);
        asm volatile("s_waitcnt lgkmcnt(0)" ::: "memory");   // own P-writes complete
        __builtin_amdgcn_sched_barrier(0);

        // PV: pf per qt; vf shared across both qt
        __builtin_amdgcn_s_setprio(1);
#pragma unroll
        for (int kb = 0; kb < 2; ++kb) {
            bf16x8 pf2[2];
#pragma unroll
            for (int qt = 0; qt < 2; ++qt)
                pf2[qt] = *(const bf16x8*)&p_s[((w*2 + qt)*16 + ln)*64 + ((kb*32 + g*8) ^ swzp)];
#pragma unroll
            for (int dt = 0; dt < 6; ++dt) {
                bf16x8 vf = *(const bf16x8*)&v_s[((kb*4 + g)*96 + dt*16 + ln) * 8];
#pragma unroll
                for (int qt = 0; qt < 2; ++qt)
                    acc_o[qt][dt] = __builtin_amdgcn_mfma_f32_16x16x32_bf16(pf2[qt], vf, acc_o[qt][dt], 0, 0, 0);
            }
        }
        __builtin_amdgcn_s_setprio(0);

        __syncthreads();          // drains vmcnt: next K resident; all waves done with v_s/k_s[cur]
        if (kt < 15) stageV(kt + 1);
        cur ^= 1;
    }

    // epilogue: O/l, reverse-sparse scatter into ATT [4096][2304] bf16
#pragma unroll
    for (int qt = 0; qt < 2; ++qt) {
        float inv = 1.0f / l_run[qt];
#pragma unroll
        for (int r = 0; r < 4; ++r) {
            float iv = __shfl(inv, g*4 + r, 16);
            int gq = qb0 + w*32 + qt*16 + g*4 + r;
            size_t base = ((size_t)(gq * 4 + n_idx)) * DIM + h * DH;
#pragma unroll
            for (int dt = 0; dt < 6; ++dt)
                ATT[base + dt*16 + ln] = f2bf(acc_o[qt][dt][r] * iv);
        }
    }
}

// ---------------- launch ----------------
extern "C" void kernel_launch(void* const* d_in, const int* in_sizes, int n_in,
                              void* d_out, int out_size, void* d_ws, size_t ws_size,
                              hipStream_t stream) {
    const float* hidden = (const float*)d_in[0];
    const float* wq = (const float*)d_in[1];
    const float* bq = (const float*)d_in[2];
    const float* wk = (const float*)d_in[3];
    const float* bk = (const float*)d_in[4];
    const float* wv = (const float*)d_in[5];
    const float* bv = (const float*)d_in[6];
    const float* wo = (const float*)d_in[7];
    const float* bo = (const float*)d_in[8];
    float* out = (float*)d_out;

    char* ws = (char*)d_ws;
    ushort_t* Xb  = (ushort_t*)ws;                       // 4096x2304 bf16
    ushort_t* WTq = (ushort_t*)(ws + 18874368);          // [wq|wk|wv|wo]^T rows concat
    ushort_t* WTk = WTq + (size_t)DIM * DIM;
    ushort_t* WTv = WTk + (size_t)DIM * DIM;
    ushort_t* WTo = WTv + (size_t)DIM * DIM;
    ushort_t* Qb  = WTo + (size_t)DIM * DIM;             // [4][24][1024][96]
    ushort_t* Kb  = Qb + (size_t)S_TOK * DIM;            // [4][24][1024][96]
    ushort_t* Vtb = Kb + (size_t)S_TOK * DIM;            // [4][24][96][1024]  (V^T)
    ushort_t* ATT = Vtb + (size_t)S_TOK * DIM;           // [4096][2304] bf16

    cast_bf16_kernel<<<dim3(9216), dim3(256), 0, stream>>>(hidden, Xb, (S_TOK * DIM) / 4);

    // all 4 weight transposes in one launch
    wtrans_kernel<<<dim3(72, 72, 4), 256, 0, stream>>>(wq, wk, wv, wo, WTq, DIM);

    // fused QKV projection: 128^2 tiles, grid (54,32) = 1728 blocks, 4/CU
    gemm128_qkv<<<dim3(54, 32), 256, 0, stream>>>(Xb, WTq, bq, bk, bv, Qb, Kb, Vtb);

    attn_kernel<<<dim3(768), 256, 0, stream>>>(Qb, Kb, Vtb, ATT);

    // output projection: N = 2304 -> 128^2 tiles, grid (18,32) = 576 blocks
    gemm128<<<dim3(18, 32), 256, 0, stream>>>(ATT, WTo, bo, out);
}

// Round 17
// 325.616 us; speedup vs baseline: 1.0599x; 1.0599x over previous
//
#include <hip/hip_runtime.h>
#include <stdint.h>

// ---------------- problem constants (b=1, f=8, h=16, w=32) ----------------
#define S_TOK 4096
#define DIM   2304
#define NH    24
#define DH    96
#define GQ    1024     // sparse sequence length (4096/4)
#define KDIM  2304

typedef unsigned short ushort_t;
typedef __attribute__((ext_vector_type(8))) short bf16x8;   // 8 bf16 = 4 VGPRs
typedef __attribute__((ext_vector_type(4))) float f32x4;

__device__ __forceinline__ ushort_t f2bf(float x) {
    union { float f; uint32_t u; } c; c.f = x;
    uint32_t u = c.u + 0x7FFFu + ((c.u >> 16) & 1u);   // RNE
    return (ushort_t)(u >> 16);
}

#define GLDS(gp, lp) __builtin_amdgcn_global_load_lds( \
    (const __attribute__((address_space(1))) void*)(gp), \
    (__attribute__((address_space(3))) void*)(lp), 16, 0, 0)

// ---------------- elementwise cast fp32 -> bf16 ----------------
__global__ __launch_bounds__(256) void cast_bf16_kernel(const float* __restrict__ in,
                                                        ushort_t* __restrict__ out, int n4) {
    int i = blockIdx.x * 256 + threadIdx.x;
    if (i >= n4) return;
    float4 v = ((const float4*)in)[i];
    ushort4 o;
    o.x = f2bf(v.x); o.y = f2bf(v.y); o.z = f2bf(v.z); o.w = f2bf(v.w);
    ((ushort4*)out)[i] = o;
}

// ---- W [k][n] fp32 -> WT [n][k] bf16, all 4 weights in one launch (z = which) ----
__global__ __launch_bounds__(256) void wtrans_kernel(const float* __restrict__ W0,
                                                     const float* __restrict__ W1,
                                                     const float* __restrict__ W2,
                                                     const float* __restrict__ W3,
                                                     ushort_t* __restrict__ WT0, int dim) {
    __shared__ float tile[32][33];
    const int z = blockIdx.z;
    const float* W = (z == 0) ? W0 : (z == 1) ? W1 : (z == 2) ? W2 : W3;
    ushort_t* WT = WT0 + (size_t)z * dim * dim;
    const int bx = blockIdx.x * 32;   // n block
    const int by = blockIdx.y * 32;   // k block
    const int tx = threadIdx.x & 31, ty = threadIdx.x >> 5;
#pragma unroll
    for (int i = 0; i < 4; ++i)
        tile[ty + i*8][tx] = W[(size_t)(by + ty + i*8) * dim + bx + tx];
    __syncthreads();
#pragma unroll
    for (int i = 0; i < 4; ++i)
        WT[(size_t)(bx + ty + i*8) * dim + by + tx] = f2bf(tile[tx][ty + i*8]);
}

// ---------------- 256x256 GEMM, BK=32, 4-slot LDS ring, counted vmcnt ----------------
// R5-best configuration (178 us QKV, 733 TF): row-major LDS tiles [256][32] bf16,
// XOR swizzle kc' = kc ^ ((row>>1)&3); GLDS dest linear, source inverse-swizzled;
// B-fragments hoisted across both M-half phases; vmcnt(8) steady (3 tiles in flight).
template<bool FINAL>
__global__ __launch_bounds__(512, 2) void gemm256(const ushort_t* __restrict__ A,
                                                  const ushort_t* __restrict__ Bt,
                                                  const float* __restrict__ bq,
                                                  const float* __restrict__ bk,
                                                  const float* __restrict__ bv,
                                                  ushort_t* __restrict__ Qb,
                                                  ushort_t* __restrict__ Kb,
                                                  ushort_t* __restrict__ Vtb,
                                                  float* __restrict__ Cf) {
    constexpr int K  = KDIM;
    constexpr int NT = K / 32;                 // 72 K-tiles
    __shared__ ushort_t a_s[4 * 8192];         // 4 slots x [256][32] bf16 = 64 KB
    __shared__ ushort_t b_s[4 * 8192];
    const int t = threadIdx.x, l = t & 63, w = t >> 6;
    const int wr = w >> 2, wc = w & 3, g = l >> 4, ln = l & 15;
    // XCD-bijective swizzle (grids are multiples of 8)
    const int nwg = gridDim.x * gridDim.y;
    const int lin = blockIdx.y * gridDim.x + blockIdx.x;
    const int cpx = nwg >> 3;
    const int swz = (lin & 7) * cpx + (lin >> 3);
    const int bx = swz % gridDim.x, by = swz / gridDim.x;
    const int m0 = by * 256, n0 = bx * 256;

    // read-side swizzle (row&7 == ln&7 in all fragment reads)
    const int swz_rd = (g ^ ((ln >> 1) & 3)) * 8;
    // stage-side inverse swizzle (per-thread constant, elements)
    const int kc_src = (((t & 3) ^ ((t >> 3) & 3)) * 8);
    const int srow   = t >> 2;                 // staging row (within 128-row half)

    auto stageA = [&](int kt) {
        const int slot = kt & 3;
#pragma unroll
        for (int q = 0; q < 2; ++q)
            GLDS(A + (size_t)(m0 + q*128 + srow) * K + kt*32 + kc_src,
                 &a_s[slot*8192 + (q*512 + t) * 8]);
    };
    auto stageB = [&](int kt) {
        const int slot = kt & 3;
#pragma unroll
        for (int q = 0; q < 2; ++q)
            GLDS(Bt + (size_t)(n0 + q*128 + srow) * K + kt*32 + kc_src,
                 &b_s[slot*8192 + (q*512 + t) * 8]);
    };

    f32x4 acc[8][4] = {};

    stageA(0); stageB(0); stageA(1); stageB(1); stageA(2); stageB(2);
    asm volatile("s_waitcnt vmcnt(8)" ::: "memory");   // tile 0 landed (own lanes)
    __builtin_amdgcn_s_barrier();                       // -> landed for all waves

    for (int kt = 0; kt < NT; ++kt) {
        const int slot = kt & 3;
        bf16x8 bv4[4];                         // B-frags: read ONCE per K-step
        // ---- phase 0: M-half 0 (reads B + A-half0) ----
        {
            bf16x8 av[4];
#pragma unroll
            for (int j = 0; j < 4; ++j)
                bv4[j] = *(const bf16x8*)&b_s[slot*8192 + (wc*64 + j*16 + ln)*32 + swz_rd];
#pragma unroll
            for (int i = 0; i < 4; ++i)
                av[i] = *(const bf16x8*)&a_s[slot*8192 + (wr*128 + i*16 + ln)*32 + swz_rd];
            if (kt < NT - 3) stageA(kt + 3);
            __builtin_amdgcn_s_barrier();
            asm volatile("s_waitcnt lgkmcnt(0)" ::: "memory");
            __builtin_amdgcn_sched_barrier(0);
            __builtin_amdgcn_s_setprio(1);
#pragma unroll
            for (int i = 0; i < 4; ++i)
#pragma unroll
                for (int j = 0; j < 4; ++j)
                    acc[i][j] = __builtin_amdgcn_mfma_f32_16x16x32_bf16(av[i], bv4[j], acc[i][j], 0, 0, 0);
            __builtin_amdgcn_s_setprio(0);
        }
        // ---- phase 1: M-half 1 (reads A-half1 only; B reused from registers) ----
        {
            bf16x8 av[4];
#pragma unroll
            for (int i = 0; i < 4; ++i)
                av[i] = *(const bf16x8*)&a_s[slot*8192 + (wr*128 + 64 + i*16 + ln)*32 + swz_rd];
            if (kt < NT - 3) stageB(kt + 3);
            // counted wait: tile kt+1 landed; kt+2,kt+3 stay in flight
            if (kt <= NT - 4)      asm volatile("s_waitcnt vmcnt(8)" ::: "memory");
            else if (kt == NT - 3) asm volatile("s_waitcnt vmcnt(4)" ::: "memory");
            else                   asm volatile("s_waitcnt vmcnt(0)" ::: "memory");
            __builtin_amdgcn_s_barrier();
            asm volatile("s_waitcnt lgkmcnt(0)" ::: "memory");
            __builtin_amdgcn_sched_barrier(0);
            __builtin_amdgcn_s_setprio(1);
#pragma unroll
            for (int i = 0; i < 4; ++i)
#pragma unroll
                for (int j = 0; j < 4; ++j)
                    acc[4 + i][j] = __builtin_amdgcn_mfma_f32_16x16x32_bf16(av[i], bv4[j], acc[4 + i][j], 0, 0, 0);
            __builtin_amdgcn_s_setprio(0);
        }
    }

    if constexpr (FINAL) {
        const float* bias = bq;
#pragma unroll
        for (int i = 0; i < 8; ++i) {
            int mb = m0 + wr*128 + i*16 + g*4;
#pragma unroll
            for (int j = 0; j < 4; ++j) {
                int n = n0 + wc*64 + j*16 + ln;
                float bb = bias[n];
#pragma unroll
                for (int r = 0; r < 4; ++r)
                    Cf[(size_t)(mb + r) * DIM + n] = acc[i][j][r] + bb;
            }
        }
    } else {
        const int mode = bx / 9;
        const int nb = (bx - mode * 9) * 256;
        const float* bias = (mode == 0) ? bq : (mode == 1) ? bk : bv;
        if (mode == 2) {
            // V^T: [inst = r*24+h][d][q]
#pragma unroll
            for (int i = 0; i < 8; ++i) {
                int mb = m0 + wr*128 + i*16 + g*4;   // mb % 4 == 0
                int q  = mb >> 2;
#pragma unroll
                for (int j = 0; j < 4; ++j) {
                    int nm = nb + wc*64 + j*16 + ln;
                    int hh = nm / DH, d = nm - hh * DH;
                    float bb = bias[nm];
#pragma unroll
                    for (int r = 0; r < 4; ++r)
                        Vtb[(size_t)(r * NH + hh) * (DH * GQ) + (size_t)d * GQ + q] =
                            f2bf(acc[i][j][r] + bb);
                }
            }
        } else {
            ushort_t* O = (mode == 0) ? Qb : Kb;
            // Q scale folds 1/sqrt(96) AND log2(e): attn softmax runs in exp2 domain
            const float scq = (mode == 0) ? 0.1472444635222742f : 1.0f;
#pragma unroll
            for (int i = 0; i < 8; ++i) {
                int mb = m0 + wr*128 + i*16 + g*4;
#pragma unroll
                for (int jp = 0; jp < 2; ++jp) {
                    int j  = jp * 2;
                    int n1 = nb + wc*64 + j*16 + ln;    // even 16-tile -> d1%32 < 16
                    int hh = n1 / DH, d1 = n1 - hh * DH;
                    int sec = d1 >> 5, f = d1 & 15;
                    float invf = __expf((float)f * -0.5756462732485114f);  // 10000^(-f/16)
                    float b1 = bias[n1], b2 = bias[n1 + 16];
#pragma unroll
                    for (int r = 0; r < 4; ++r) {
                        int m = mb + r;
                        int pos = (sec == 0) ? (m >> 9) : (sec == 1) ? ((m >> 5) & 15) : (m & 31);
                        float ang = (float)pos * invf;
                        float sn, cs;
                        __sincosf(ang, &sn, &cs);
                        float v1 = acc[i][j][r]     + b1;
                        float v2 = acc[i][j + 1][r] + b2;
                        size_t base = ((size_t)((m & 3) * NH + hh)) * (GQ * DH) + (size_t)(m >> 2) * DH;
                        O[base + d1]      = f2bf((v1 * cs - v2 * sn) * scq);
                        O[base + d1 + 16] = f2bf((v2 * cs + v1 * sn) * scq);
                    }
                }
            }
        }
    }
}

// ---------------- 128x128 GEMM (final projection), 2-slot double buffer ----------
__global__ __launch_bounds__(256) void gemm128(const ushort_t* __restrict__ A,
                                               const ushort_t* __restrict__ Bt,
                                               const float* __restrict__ bias,
                                               float* __restrict__ C) {
    constexpr int K  = KDIM;
    constexpr int NT = K / 32;                 // 72 K-tiles
    __shared__ ushort_t a_s[2 * 4096];         // 2 slots x [128][32] bf16 = 16 KB
    __shared__ ushort_t b_s[2 * 4096];
    const int t = threadIdx.x;
    const int l = t & 63, w = t >> 6;
    const int wr = w >> 1, wc = w & 1;
    const int g = l >> 4, ln = l & 15;
    // grid (18,32) = 576 blocks; bijective XCD swizzle (576 % 8 == 0)
    const int lin = blockIdx.y * gridDim.x + blockIdx.x;
    const int swz = (lin & 7) * 72 + (lin >> 3);
    const int bx = swz % 18, by = swz / 18;
    const int m0 = by * 128, n0 = bx * 128;

    const int swz_rd = (g ^ ((ln >> 1) & 3)) * 8;            // read-side swizzle
    const int kc_src = (((t & 3) ^ ((t >> 3) & 3)) * 8);     // stage-side inverse
    const int srow   = t >> 2;                                // 0..63

    const ushort_t* Ab = A  + (size_t)(m0 + srow) * K + kc_src;
    const ushort_t* Bb = Bt + (size_t)(n0 + srow) * K + kc_src;
    const size_t rstep = (size_t)64 * K;

    auto stage = [&](int kt) {
        const int slot = kt & 1;
        GLDS(Ab + kt*32,         &a_s[slot*4096 + t*8]);
        GLDS(Ab + rstep + kt*32, &a_s[slot*4096 + 2048 + t*8]);
        GLDS(Bb + kt*32,         &b_s[slot*4096 + t*8]);
        GLDS(Bb + rstep + kt*32, &b_s[slot*4096 + 2048 + t*8]);
    };

    f32x4 acc[4][4] = {};

    stage(0); stage(1);
    asm volatile("s_waitcnt vmcnt(4)" ::: "memory");   // tile 0 landed (own lanes)
    __builtin_amdgcn_s_barrier();                      // -> landed for all waves

    for (int kt = 0; kt < NT; ++kt) {
        const int slot = kt & 1;
        bf16x8 av[4], bv[4];
#pragma unroll
        for (int i = 0; i < 4; ++i)
            av[i] = *(const bf16x8*)&a_s[slot*4096 + (wr*64 + i*16 + ln) * 32 + swz_rd];
#pragma unroll
        for (int j = 0; j < 4; ++j)
            bv[j] = *(const bf16x8*)&b_s[slot*4096 + (wc*64 + j*16 + ln) * 32 + swz_rd];
        asm volatile("s_waitcnt lgkmcnt(0)" ::: "memory");   // own reads of slot done
        __builtin_amdgcn_sched_barrier(0);
        __builtin_amdgcn_s_barrier();                        // ALL waves done with slot
        if (kt < NT - 2) {
            stage(kt + 2);                                   // overwrite slot safely
            asm volatile("s_waitcnt vmcnt(4)" ::: "memory"); // tile kt+1 landed
        } else {
            asm volatile("s_waitcnt vmcnt(0)" ::: "memory");
        }
        __builtin_amdgcn_sched_barrier(0);
        __builtin_amdgcn_s_setprio(1);
#pragma unroll
        for (int i = 0; i < 4; ++i)
#pragma unroll
            for (int j = 0; j < 4; ++j)
                acc[i][j] = __builtin_amdgcn_mfma_f32_16x16x32_bf16(av[i], bv[j], acc[i][j], 0, 0, 0);
        __builtin_amdgcn_s_setprio(0);
        __builtin_amdgcn_sched_barrier(0);
        __builtin_amdgcn_s_barrier();      // all waves passed vmcnt -> next tile readable
    }

#pragma unroll
    for (int i = 0; i < 4; ++i) {
        int mb = m0 + wr*64 + i*16 + g*4;
#pragma unroll
        for (int j = 0; j < 4; ++j) {
            int n = n0 + wc*64 + j*16 + ln;
            float bb = bias[n];
#pragma unroll
            for (int r = 0; r < 4; ++r)
                C[(size_t)(mb + r) * DIM + n] = acc[i][j][r] + bb;
        }
    }
}

// ---------------- flash attention: 96 instances of [1024,96], V^T input ----------------
// R15 structure: exp2-domain softmax, exact defer-rescale, setprio clusters.
// 4 waves x 32 q-rows, KV tile 64, 52 KB LDS -> 3 blocks/CU.
__global__ __launch_bounds__(256, 3) void attn_kernel(const ushort_t* __restrict__ Qb,
                                                      const ushort_t* __restrict__ Kb,
                                                      const ushort_t* __restrict__ Vt,
                                                      ushort_t* __restrict__ ATT) {
    __shared__ ushort_t k_s[2][12 * 64 * 8];   // [buf][d-chunk][key][8]  24KB
    __shared__ ushort_t v_s[8 * 96 * 8];       // [key-chunk][d][8]       12KB
    __shared__ ushort_t p_s[4 * 2 * 16 * 64];  // [wave][qt][q16][key64]  16KB (XOR-swizzled)

    const int t = threadIdx.x, l = t & 63, w = t >> 6, g = l >> 4, ln = l & 15;
    // XCD-bijective swizzle: 768 blocks -> 96/XCD = 12 whole instances
    const int lin  = blockIdx.x;
    const int swz  = (lin & 7) * 96 + (lin >> 3);
    const int inst = swz >> 3;            // 0..95
    const int qb0  = (swz & 7) * 128;
    const int n_idx = inst / NH, h = inst - n_idx * NH;
    const int swzp = (ln & 7) << 3;       // P-LDS XOR swizzle (ushort units)

    const ushort_t* Qi = Qb + (size_t)inst * (GQ * DH);
    const ushort_t* Ki = Kb + (size_t)inst * (GQ * DH);
    const ushort_t* Vi = Vt + (size_t)inst * (DH * GQ);   // [96][1024]

    auto stageK = [&](int kt, int b) {
#pragma unroll
        for (int it = 0; it < 3; ++it) {
            int P = t + it * 256;              // 0..767 = [c<12][key<64]
            int c = P >> 6, key = P & 63;
            GLDS(Ki + (size_t)(kt * 64 + key) * DH + c * 8, &k_s[b][P * 8]);
        }
    };
    auto stageV = [&](int kt) {
#pragma unroll
        for (int it = 0; it < 3; ++it) {
            int P = t + it * 256;              // 0..767 = [c<8][d<96]
            int c = P / 96, d = P - c * 96;
            GLDS(Vi + (size_t)d * GQ + kt * 64 + c * 8, &v_s[P * 8]);
        }
    };

    // Q fragments (used as MFMA B-operand); Q carries log2e/sqrt(96)
    bf16x8 qf[2][3];
#pragma unroll
    for (int qt = 0; qt < 2; ++qt)
#pragma unroll
        for (int ks = 0; ks < 3; ++ks)
            qf[qt][ks] = *(const bf16x8*)(Qi + (size_t)(qb0 + w*32 + qt*16 + ln) * DH + ks*32 + g*8);

    float m_run[2], l_run[2];
#pragma unroll
    for (int qt = 0; qt < 2; ++qt) { m_run[qt] = -3.0e38f; l_run[qt] = 0.f; }
    f32x4 acc_o[2][6] = {};

    stageK(0, 0);
    stageV(0);
    __syncthreads();

    int cur = 0;
    for (int kt = 0; kt < 16; ++kt) {
        stageK((kt + 1) & 15, cur ^ 1);       // prefetch next K (3 GLDS in flight)
        float al2[2];
        bool grew[2];

        // S^T = K Q^T : lane holds q = ln, keys = ct*16 + g*4 + r  (exp2 domain)
        f32x4 sc[2][4] = {};
        __builtin_amdgcn_s_setprio(1);
#pragma unroll
        for (int ct = 0; ct < 4; ++ct) {
            bf16x8 kf0 = *(const bf16x8*)&k_s[cur][((0*4 + g)*64 + ct*16 + ln) * 8];
            bf16x8 kf1 = *(const bf16x8*)&k_s[cur][((1*4 + g)*64 + ct*16 + ln) * 8];
            bf16x8 kf2 = *(const bf16x8*)&k_s[cur][((2*4 + g)*64 + ct*16 + ln) * 8];
#pragma unroll
            for (int qi = 0; qi < 2; ++qi) {
                sc[qi][ct] = __builtin_amdgcn_mfma_f32_16x16x32_bf16(kf0, qf[qi][0], sc[qi][ct], 0, 0, 0);
                sc[qi][ct] = __builtin_amdgcn_mfma_f32_16x16x32_bf16(kf1, qf[qi][1], sc[qi][ct], 0, 0, 0);
                sc[qi][ct] = __builtin_amdgcn_mfma_f32_16x16x32_bf16(kf2, qf[qi][2], sc[qi][ct], 0, 0, 0);
            }
        }
        __builtin_amdgcn_s_setprio(0);
#pragma unroll
        for (int qi = 0; qi < 2; ++qi) {
            const int qt = qi;
            float mx = sc[qi][0][0];
#pragma unroll
            for (int ct = 0; ct < 4; ++ct)
#pragma unroll
                for (int r = 0; r < 4; ++r)
                    mx = fmaxf(mx, sc[qi][ct][r]);
            mx = fmaxf(mx, __shfl_xor(mx, 16, 64));
            mx = fmaxf(mx, __shfl_xor(mx, 32, 64));
            // exact defer: if no lane's max grew, keep m_run (P <= 1 still holds)
            bool grow = !__all(mx <= m_run[qt]);
            float al = 1.0f;
            if (grow) {
                float mn = fmaxf(m_run[qt], mx);
                al = __builtin_amdgcn_exp2f(m_run[qt] - mn);
                m_run[qt] = mn;
            }
            grew[qi] = grow;
            float rs = 0.f;
            ushort_t pb[16];
#pragma unroll
            for (int ct = 0; ct < 4; ++ct)
#pragma unroll
                for (int r = 0; r < 4; ++r) {
                    float p = __builtin_amdgcn_exp2f(sc[qi][ct][r] - m_run[qt]);
                    rs += p;
                    pb[ct*4 + r] = f2bf(p);
                }
            rs += __shfl_xor(rs, 16, 64);
            rs += __shfl_xor(rs, 32, 64);
            l_run[qt] = l_run[qt] * al + rs;
            al2[qt] = al;
            const int pbase = ((w*2 + qt)*16 + ln) * 64;
#pragma unroll
            for (int ct = 0; ct < 4; ++ct) {
                ushort4 pk;
                pk.x = pb[ct*4+0]; pk.y = pb[ct*4+1]; pk.z = pb[ct*4+2]; pk.w = pb[ct*4+3];
                *(ushort4*)&p_s[pbase + ((ct*16 + g*4) ^ swzp)] = pk;
            }
        }

        // rescale O by exp2(m_old - m_new) only when some row's max grew
        if (grew[0] || grew[1]) {
#pragma unroll
            for (int qt = 0; qt < 2; ++qt)
#pragma unroll
                for (int r = 0; r < 4; ++r) {
                    float a = __shfl(al2[qt], g*4 + r, 16);
#pragma unroll
                    for (int dt = 0; dt < 6; ++dt)
                        acc_o[qt][dt][r] *= a;
                }
        }

        // V(kt) landed (3 K-prefetch remain in flight); cross-wave visibility
        asm volatile("s_waitcnt vmcnt(3)" ::: "memory");
        __builtin_amdgcn_s_barrier();
        __builtin_amdgcn_sched_barrier(0);
        asm volatile("s_waitcnt lgkmcnt(0)" ::: "memory");   // own P-writes complete
        __builtin_amdgcn_sched_barrier(0);

        // PV: pf per qt; vf shared across both qt
        __builtin_amdgcn_s_setprio(1);
#pragma unroll
        for (int kb = 0; kb < 2; ++kb) {
            bf16x8 pf2[2];
#pragma unroll
            for (int qt = 0; qt < 2; ++qt)
                pf2[qt] = *(const bf16x8*)&p_s[((w*2 + qt)*16 + ln)*64 + ((kb*32 + g*8) ^ swzp)];
#pragma unroll
            for (int dt = 0; dt < 6; ++dt) {
                bf16x8 vf = *(const bf16x8*)&v_s[((kb*4 + g)*96 + dt*16 + ln) * 8];
#pragma unroll
                for (int qt = 0; qt < 2; ++qt)
                    acc_o[qt][dt] = __builtin_amdgcn_mfma_f32_16x16x32_bf16(pf2[qt], vf, acc_o[qt][dt], 0, 0, 0);
            }
        }
        __builtin_amdgcn_s_setprio(0);

        __syncthreads();          // drains vmcnt: next K resident; all waves done with v_s/k_s[cur]
        if (kt < 15) stageV(kt + 1);
        cur ^= 1;
    }

    // epilogue: O/l, reverse-sparse scatter into ATT [4096][2304] bf16
#pragma unroll
    for (int qt = 0; qt < 2; ++qt) {
        float inv = 1.0f / l_run[qt];
#pragma unroll
        for (int r = 0; r < 4; ++r) {
            float iv = __shfl(inv, g*4 + r, 16);
            int gq = qb0 + w*32 + qt*16 + g*4 + r;
            size_t base = ((size_t)(gq * 4 + n_idx)) * DIM + h * DH;
#pragma unroll
            for (int dt = 0; dt < 6; ++dt)
                ATT[base + dt*16 + ln] = f2bf(acc_o[qt][dt][r] * iv);
        }
    }
}

// ---------------- launch ----------------
extern "C" void kernel_launch(void* const* d_in, const int* in_sizes, int n_in,
                              void* d_out, int out_size, void* d_ws, size_t ws_size,
                              hipStream_t stream) {
    const float* hidden = (const float*)d_in[0];
    const float* wq = (const float*)d_in[1];
    const float* bq = (const float*)d_in[2];
    const float* wk = (const float*)d_in[3];
    const float* bk = (const float*)d_in[4];
    const float* wv = (const float*)d_in[5];
    const float* bv = (const float*)d_in[6];
    const float* wo = (const float*)d_in[7];
    const float* bo = (const float*)d_in[8];
    float* out = (float*)d_out;

    char* ws = (char*)d_ws;
    ushort_t* Xb  = (ushort_t*)ws;                       // 4096x2304 bf16
    ushort_t* WTq = (ushort_t*)(ws + 18874368);          // [wq|wk|wv|wo]^T rows concat
    ushort_t* WTk = WTq + (size_t)DIM * DIM;
    ushort_t* WTv = WTk + (size_t)DIM * DIM;
    ushort_t* WTo = WTv + (size_t)DIM * DIM;
    ushort_t* Qb  = WTo + (size_t)DIM * DIM;             // [4][24][1024][96]
    ushort_t* Kb  = Qb + (size_t)S_TOK * DIM;            // [4][24][1024][96]
    ushort_t* Vtb = Kb + (size_t)S_TOK * DIM;            // [4][24][96][1024]  (V^T)
    ushort_t* ATT = Vtb + (size_t)S_TOK * DIM;           // [4096][2304] bf16

    cast_bf16_kernel<<<dim3(9216), dim3(256), 0, stream>>>(hidden, Xb, (S_TOK * DIM) / 4);

    // all 4 weight transposes in one launch
    wtrans_kernel<<<dim3(72, 72, 4), 256, 0, stream>>>(wq, wk, wv, wo, WTq, DIM);

    // fused QKV projection: N = 3*2304 = 6912 -> grid (27,16) = 432 blocks
    gemm256<false><<<dim3(27, 16), 512, 0, stream>>>(Xb, WTq, bq, bk, bv, Qb, Kb, Vtb, nullptr);

    attn_kernel<<<dim3(768), 256, 0, stream>>>(Qb, Kb, Vtb, ATT);

    // output projection: N = 2304 -> 128^2 tiles, grid (18,32) = 576 blocks
    gemm128<<<dim3(18, 32), 256, 0, stream>>>(ATT, WTo, bo, out);
}

// Round 18
// 317.691 us; speedup vs baseline: 1.0864x; 1.0249x over previous
//
#include <hip/hip_runtime.h>
#include <stdint.h>

// ---------------- problem constants (b=1, f=8, h=16, w=32) ----------------
#define S_TOK 4096
#define DIM   2304
#define NH    24
#define DH    96
#define GQ    1024     // sparse sequence length (4096/4)
#define KDIM  2304

typedef unsigned short ushort_t;
typedef __attribute__((ext_vector_type(8))) short bf16x8;   // 8 bf16 = 4 VGPRs
typedef __attribute__((ext_vector_type(4))) float f32x4;

__device__ __forceinline__ ushort_t f2bf(float x) {
    union { float f; uint32_t u; } c; c.f = x;
    uint32_t u = c.u + 0x7FFFu + ((c.u >> 16) & 1u);   // RNE
    return (ushort_t)(u >> 16);
}

#define GLDS(gp, lp) __builtin_amdgcn_global_load_lds( \
    (const __attribute__((address_space(1))) void*)(gp), \
    (__attribute__((address_space(3))) void*)(lp), 16, 0, 0)

// ---- prep: z<4 -> W_z [k][n] fp32 -> WT [n][k] bf16 ; z==4 -> cast hidden ----
__global__ __launch_bounds__(256) void prep_kernel(const float* __restrict__ hidden,
                                                   const float* __restrict__ W0,
                                                   const float* __restrict__ W1,
                                                   const float* __restrict__ W2,
                                                   const float* __restrict__ W3,
                                                   ushort_t* __restrict__ WT0,
                                                   ushort_t* __restrict__ Xb, int dim) {
    const int z = blockIdx.z;
    if (z == 4) {
        // cast 4096x2304 fp32 -> bf16 (2 float4 per thread)
        const int n4 = (S_TOK * DIM) / 4;
        int base = (blockIdx.y * gridDim.x + blockIdx.x) * 256 + threadIdx.x;
#pragma unroll
        for (int rep = 0; rep < 2; ++rep) {
            int i = base + rep * (72 * 72 * 256);
            if (i < n4) {
                float4 v = ((const float4*)hidden)[i];
                ushort4 o;
                o.x = f2bf(v.x); o.y = f2bf(v.y); o.z = f2bf(v.z); o.w = f2bf(v.w);
                ((ushort4*)Xb)[i] = o;
            }
        }
        return;
    }
    __shared__ float tile[32][33];
    const float* W = (z == 0) ? W0 : (z == 1) ? W1 : (z == 2) ? W2 : W3;
    ushort_t* WT = WT0 + (size_t)z * dim * dim;
    const int bx = blockIdx.x * 32;   // n block
    const int by = blockIdx.y * 32;   // k block
    const int tx = threadIdx.x & 31, ty = threadIdx.x >> 5;
#pragma unroll
    for (int i = 0; i < 4; ++i)
        tile[ty + i*8][tx] = W[(size_t)(by + ty + i*8) * dim + bx + tx];
    __syncthreads();
#pragma unroll
    for (int i = 0; i < 4; ++i)
        WT[(size_t)(bx + ty + i*8) * dim + by + tx] = f2bf(tile[tx][ty + i*8]);
}

// ---------------- 256x256 GEMM, BK=32, 4-slot LDS ring, counted vmcnt ----------------
// R5-best configuration (178 us QKV, 733 TF): row-major LDS tiles [256][32] bf16,
// XOR swizzle kc' = kc ^ ((row>>1)&3); GLDS dest linear, source inverse-swizzled;
// B-fragments hoisted across both M-half phases; vmcnt(8) steady (3 tiles in flight).
template<bool FINAL>
__global__ __launch_bounds__(512, 2) void gemm256(const ushort_t* __restrict__ A,
                                                  const ushort_t* __restrict__ Bt,
                                                  const float* __restrict__ bq,
                                                  const float* __restrict__ bk,
                                                  const float* __restrict__ bv,
                                                  ushort_t* __restrict__ Qb,
                                                  ushort_t* __restrict__ Kb,
                                                  ushort_t* __restrict__ Vtb,
                                                  float* __restrict__ Cf) {
    constexpr int K  = KDIM;
    constexpr int NT = K / 32;                 // 72 K-tiles
    __shared__ ushort_t a_s[4 * 8192];         // 4 slots x [256][32] bf16 = 64 KB
    __shared__ ushort_t b_s[4 * 8192];
    const int t = threadIdx.x, l = t & 63, w = t >> 6;
    const int wr = w >> 2, wc = w & 3, g = l >> 4, ln = l & 15;
    // XCD-bijective swizzle (grids are multiples of 8)
    const int nwg = gridDim.x * gridDim.y;
    const int lin = blockIdx.y * gridDim.x + blockIdx.x;
    const int cpx = nwg >> 3;
    const int swz = (lin & 7) * cpx + (lin >> 3);
    const int bx = swz % gridDim.x, by = swz / gridDim.x;
    const int m0 = by * 256, n0 = bx * 256;

    // read-side swizzle (row&7 == ln&7 in all fragment reads)
    const int swz_rd = (g ^ ((ln >> 1) & 3)) * 8;
    // stage-side inverse swizzle (per-thread constant, elements)
    const int kc_src = (((t & 3) ^ ((t >> 3) & 3)) * 8);
    const int srow   = t >> 2;                 // staging row (within 128-row half)

    auto stageA = [&](int kt) {
        const int slot = kt & 3;
#pragma unroll
        for (int q = 0; q < 2; ++q)
            GLDS(A + (size_t)(m0 + q*128 + srow) * K + kt*32 + kc_src,
                 &a_s[slot*8192 + (q*512 + t) * 8]);
    };
    auto stageB = [&](int kt) {
        const int slot = kt & 3;
#pragma unroll
        for (int q = 0; q < 2; ++q)
            GLDS(Bt + (size_t)(n0 + q*128 + srow) * K + kt*32 + kc_src,
                 &b_s[slot*8192 + (q*512 + t) * 8]);
    };

    f32x4 acc[8][4] = {};

    stageA(0); stageB(0); stageA(1); stageB(1); stageA(2); stageB(2);
    asm volatile("s_waitcnt vmcnt(8)" ::: "memory");   // tile 0 landed (own lanes)
    __builtin_amdgcn_s_barrier();                       // -> landed for all waves

    for (int kt = 0; kt < NT; ++kt) {
        const int slot = kt & 3;
        bf16x8 bv4[4];                         // B-frags: read ONCE per K-step
        // ---- phase 0: M-half 0 (reads B + A-half0) ----
        {
            bf16x8 av[4];
#pragma unroll
            for (int j = 0; j < 4; ++j)
                bv4[j] = *(const bf16x8*)&b_s[slot*8192 + (wc*64 + j*16 + ln)*32 + swz_rd];
#pragma unroll
            for (int i = 0; i < 4; ++i)
                av[i] = *(const bf16x8*)&a_s[slot*8192 + (wr*128 + i*16 + ln)*32 + swz_rd];
            if (kt < NT - 3) stageA(kt + 3);
            __builtin_amdgcn_s_barrier();
            asm volatile("s_waitcnt lgkmcnt(0)" ::: "memory");
            __builtin_amdgcn_sched_barrier(0);
            __builtin_amdgcn_s_setprio(1);
#pragma unroll
            for (int i = 0; i < 4; ++i)
#pragma unroll
                for (int j = 0; j < 4; ++j)
                    acc[i][j] = __builtin_amdgcn_mfma_f32_16x16x32_bf16(av[i], bv4[j], acc[i][j], 0, 0, 0);
            __builtin_amdgcn_s_setprio(0);
        }
        // ---- phase 1: M-half 1 (reads A-half1 only; B reused from registers) ----
        {
            bf16x8 av[4];
#pragma unroll
            for (int i = 0; i < 4; ++i)
                av[i] = *(const bf16x8*)&a_s[slot*8192 + (wr*128 + 64 + i*16 + ln)*32 + swz_rd];
            if (kt < NT - 3) stageB(kt + 3);
            // counted wait: tile kt+1 landed; kt+2,kt+3 stay in flight
            if (kt <= NT - 4)      asm volatile("s_waitcnt vmcnt(8)" ::: "memory");
            else if (kt == NT - 3) asm volatile("s_waitcnt vmcnt(4)" ::: "memory");
            else                   asm volatile("s_waitcnt vmcnt(0)" ::: "memory");
            __builtin_amdgcn_s_barrier();
            asm volatile("s_waitcnt lgkmcnt(0)" ::: "memory");
            __builtin_amdgcn_sched_barrier(0);
            __builtin_amdgcn_s_setprio(1);
#pragma unroll
            for (int i = 0; i < 4; ++i)
#pragma unroll
                for (int j = 0; j < 4; ++j)
                    acc[4 + i][j] = __builtin_amdgcn_mfma_f32_16x16x32_bf16(av[i], bv4[j], acc[4 + i][j], 0, 0, 0);
            __builtin_amdgcn_s_setprio(0);
        }
    }

    if constexpr (FINAL) {
        const float* bias = bq;
#pragma unroll
        for (int i = 0; i < 8; ++i) {
            int mb = m0 + wr*128 + i*16 + g*4;
#pragma unroll
            for (int j = 0; j < 4; ++j) {
                int n = n0 + wc*64 + j*16 + ln;
                float bb = bias[n];
#pragma unroll
                for (int r = 0; r < 4; ++r)
                    Cf[(size_t)(mb + r) * DIM + n] = acc[i][j][r] + bb;
            }
        }
    } else {
        const int mode = bx / 9;
        const int nb = (bx - mode * 9) * 256;
        const float* bias = (mode == 0) ? bq : (mode == 1) ? bk : bv;
        if (mode == 2) {
            // V^T: [inst = r*24+h][d][q]
#pragma unroll
            for (int i = 0; i < 8; ++i) {
                int mb = m0 + wr*128 + i*16 + g*4;   // mb % 4 == 0
                int q  = mb >> 2;
#pragma unroll
                for (int j = 0; j < 4; ++j) {
                    int nm = nb + wc*64 + j*16 + ln;
                    int hh = nm / DH, d = nm - hh * DH;
                    float bb = bias[nm];
#pragma unroll
                    for (int r = 0; r < 4; ++r)
                        Vtb[(size_t)(r * NH + hh) * (DH * GQ) + (size_t)d * GQ + q] =
                            f2bf(acc[i][j][r] + bb);
                }
            }
        } else {
            ushort_t* O = (mode == 0) ? Qb : Kb;
            // Q scale folds 1/sqrt(96) AND log2(e): attn softmax runs in exp2 domain
            const float scq = (mode == 0) ? 0.1472444635222742f : 1.0f;
#pragma unroll
            for (int i = 0; i < 8; ++i) {
                int mb = m0 + wr*128 + i*16 + g*4;
#pragma unroll
                for (int jp = 0; jp < 2; ++jp) {
                    int j  = jp * 2;
                    int n1 = nb + wc*64 + j*16 + ln;    // even 16-tile -> d1%32 < 16
                    int hh = n1 / DH, d1 = n1 - hh * DH;
                    int sec = d1 >> 5, f = d1 & 15;
                    float invf = __expf((float)f * -0.5756462732485114f);  // 10000^(-f/16)
                    float b1 = bias[n1], b2 = bias[n1 + 16];
#pragma unroll
                    for (int r = 0; r < 4; ++r) {
                        int m = mb + r;
                        int pos = (sec == 0) ? (m >> 9) : (sec == 1) ? ((m >> 5) & 15) : (m & 31);
                        float ang = (float)pos * invf;
                        float sn, cs;
                        __sincosf(ang, &sn, &cs);
                        float v1 = acc[i][j][r]     + b1;
                        float v2 = acc[i][j + 1][r] + b2;
                        size_t base = ((size_t)((m & 3) * NH + hh)) * (GQ * DH) + (size_t)(m >> 2) * DH;
                        O[base + d1]      = f2bf((v1 * cs - v2 * sn) * scq);
                        O[base + d1 + 16] = f2bf((v2 * cs + v1 * sn) * scq);
                    }
                }
            }
        }
    }
}

// ---------------- 128x128 GEMM (final projection), 2-slot double buffer ----------
// nt-stores for C: fp32 output is never re-read; keep ATT/WTo panels in cache.
__global__ __launch_bounds__(256) void gemm128(const ushort_t* __restrict__ A,
                                               const ushort_t* __restrict__ Bt,
                                               const float* __restrict__ bias,
                                               float* __restrict__ C) {
    constexpr int K  = KDIM;
    constexpr int NT = K / 32;                 // 72 K-tiles
    __shared__ ushort_t a_s[2 * 4096];         // 2 slots x [128][32] bf16 = 16 KB
    __shared__ ushort_t b_s[2 * 4096];
    const int t = threadIdx.x;
    const int l = t & 63, w = t >> 6;
    const int wr = w >> 1, wc = w & 1;
    const int g = l >> 4, ln = l & 15;
    // grid (18,32) = 576 blocks; bijective XCD swizzle (576 % 8 == 0)
    const int lin = blockIdx.y * gridDim.x + blockIdx.x;
    const int swz = (lin & 7) * 72 + (lin >> 3);
    const int bx = swz % 18, by = swz / 18;
    const int m0 = by * 128, n0 = bx * 128;

    const int swz_rd = (g ^ ((ln >> 1) & 3)) * 8;            // read-side swizzle
    const int kc_src = (((t & 3) ^ ((t >> 3) & 3)) * 8);     // stage-side inverse
    const int srow   = t >> 2;                                // 0..63

    const ushort_t* Ab = A  + (size_t)(m0 + srow) * K + kc_src;
    const ushort_t* Bb = Bt + (size_t)(n0 + srow) * K + kc_src;
    const size_t rstep = (size_t)64 * K;

    auto stage = [&](int kt) {
        const int slot = kt & 1;
        GLDS(Ab + kt*32,         &a_s[slot*4096 + t*8]);
        GLDS(Ab + rstep + kt*32, &a_s[slot*4096 + 2048 + t*8]);
        GLDS(Bb + kt*32,         &b_s[slot*4096 + t*8]);
        GLDS(Bb + rstep + kt*32, &b_s[slot*4096 + 2048 + t*8]);
    };

    f32x4 acc[4][4] = {};

    stage(0); stage(1);
    asm volatile("s_waitcnt vmcnt(4)" ::: "memory");   // tile 0 landed (own lanes)
    __builtin_amdgcn_s_barrier();                      // -> landed for all waves

    for (int kt = 0; kt < NT; ++kt) {
        const int slot = kt & 1;
        bf16x8 av[4], bv[4];
#pragma unroll
        for (int i = 0; i < 4; ++i)
            av[i] = *(const bf16x8*)&a_s[slot*4096 + (wr*64 + i*16 + ln) * 32 + swz_rd];
#pragma unroll
        for (int j = 0; j < 4; ++j)
            bv[j] = *(const bf16x8*)&b_s[slot*4096 + (wc*64 + j*16 + ln) * 32 + swz_rd];
        asm volatile("s_waitcnt lgkmcnt(0)" ::: "memory");   // own reads of slot done
        __builtin_amdgcn_sched_barrier(0);
        __builtin_amdgcn_s_barrier();                        // ALL waves done with slot
        if (kt < NT - 2) {
            stage(kt + 2);                                   // overwrite slot safely
            asm volatile("s_waitcnt vmcnt(4)" ::: "memory"); // tile kt+1 landed
        } else {
            asm volatile("s_waitcnt vmcnt(0)" ::: "memory");
        }
        __builtin_amdgcn_sched_barrier(0);
        __builtin_amdgcn_s_setprio(1);
#pragma unroll
        for (int i = 0; i < 4; ++i)
#pragma unroll
            for (int j = 0; j < 4; ++j)
                acc[i][j] = __builtin_amdgcn_mfma_f32_16x16x32_bf16(av[i], bv[j], acc[i][j], 0, 0, 0);
        __builtin_amdgcn_s_setprio(0);
        __builtin_amdgcn_sched_barrier(0);
        __builtin_amdgcn_s_barrier();      // all waves passed vmcnt -> next tile readable
    }

#pragma unroll
    for (int i = 0; i < 4; ++i) {
        int mb = m0 + wr*64 + i*16 + g*4;
#pragma unroll
        for (int j = 0; j < 4; ++j) {
            int n = n0 + wc*64 + j*16 + ln;
            float bb = bias[n];
#pragma unroll
            for (int r = 0; r < 4; ++r)
                __builtin_nontemporal_store(acc[i][j][r] + bb,
                                            &C[(size_t)(mb + r) * DIM + n]);
        }
    }
}

// ---------------- flash attention: 96 instances of [1024,96], V^T input ----------------
// R15 structure: exp2-domain softmax, exact defer-rescale, setprio clusters.
// 4 waves x 32 q-rows, KV tile 64, 52 KB LDS -> 3 blocks/CU.
__global__ __launch_bounds__(256, 3) void attn_kernel(const ushort_t* __restrict__ Qb,
                                                      const ushort_t* __restrict__ Kb,
                                                      const ushort_t* __restrict__ Vt,
                                                      ushort_t* __restrict__ ATT) {
    __shared__ ushort_t k_s[2][12 * 64 * 8];   // [buf][d-chunk][key][8]  24KB
    __shared__ ushort_t v_s[8 * 96 * 8];       // [key-chunk][d][8]       12KB
    __shared__ ushort_t p_s[4 * 2 * 16 * 64];  // [wave][qt][q16][key64]  16KB (XOR-swizzled)

    const int t = threadIdx.x, l = t & 63, w = t >> 6, g = l >> 4, ln = l & 15;
    // XCD-bijective swizzle: 768 blocks -> 96/XCD = 12 whole instances
    const int lin  = blockIdx.x;
    const int swz  = (lin & 7) * 96 + (lin >> 3);
    const int inst = swz >> 3;            // 0..95
    const int qb0  = (swz & 7) * 128;
    const int n_idx = inst / NH, h = inst - n_idx * NH;
    const int swzp = (ln & 7) << 3;       // P-LDS XOR swizzle (ushort units)

    const ushort_t* Qi = Qb + (size_t)inst * (GQ * DH);
    const ushort_t* Ki = Kb + (size_t)inst * (GQ * DH);
    const ushort_t* Vi = Vt + (size_t)inst * (DH * GQ);   // [96][1024]

    auto stageK = [&](int kt, int b) {
#pragma unroll
        for (int it = 0; it < 3; ++it) {
            int P = t + it * 256;              // 0..767 = [c<12][key<64]
            int c = P >> 6, key = P & 63;
            GLDS(Ki + (size_t)(kt * 64 + key) * DH + c * 8, &k_s[b][P * 8]);
        }
    };
    auto stageV = [&](int kt) {
#pragma unroll
        for (int it = 0; it < 3; ++it) {
            int P = t + it * 256;              // 0..767 = [c<8][d<96]
            int c = P / 96, d = P - c * 96;
            GLDS(Vi + (size_t)d * GQ + kt * 64 + c * 8, &v_s[P * 8]);
        }
    };

    // Q fragments (used as MFMA B-operand); Q carries log2e/sqrt(96)
    bf16x8 qf[2][3];
#pragma unroll
    for (int qt = 0; qt < 2; ++qt)
#pragma unroll
        for (int ks = 0; ks < 3; ++ks)
            qf[qt][ks] = *(const bf16x8*)(Qi + (size_t)(qb0 + w*32 + qt*16 + ln) * DH + ks*32 + g*8);

    float m_run[2], l_run[2];
#pragma unroll
    for (int qt = 0; qt < 2; ++qt) { m_run[qt] = -3.0e38f; l_run[qt] = 0.f; }
    f32x4 acc_o[2][6] = {};

    stageK(0, 0);
    stageV(0);
    __syncthreads();

    int cur = 0;
    for (int kt = 0; kt < 16; ++kt) {
        stageK((kt + 1) & 15, cur ^ 1);       // prefetch next K (3 GLDS in flight)
        float al2[2];
        bool grew[2];

        // S^T = K Q^T : lane holds q = ln, keys = ct*16 + g*4 + r  (exp2 domain)
        f32x4 sc[2][4] = {};
        __builtin_amdgcn_s_setprio(1);
#pragma unroll
        for (int ct = 0; ct < 4; ++ct) {
            bf16x8 kf0 = *(const bf16x8*)&k_s[cur][((0*4 + g)*64 + ct*16 + ln) * 8];
            bf16x8 kf1 = *(const bf16x8*)&k_s[cur][((1*4 + g)*64 + ct*16 + ln) * 8];
            bf16x8 kf2 = *(const bf16x8*)&k_s[cur][((2*4 + g)*64 + ct*16 + ln) * 8];
#pragma unroll
            for (int qi = 0; qi < 2; ++qi) {
                sc[qi][ct] = __builtin_amdgcn_mfma_f32_16x16x32_bf16(kf0, qf[qi][0], sc[qi][ct], 0, 0, 0);
                sc[qi][ct] = __builtin_amdgcn_mfma_f32_16x16x32_bf16(kf1, qf[qi][1], sc[qi][ct], 0, 0, 0);
                sc[qi][ct] = __builtin_amdgcn_mfma_f32_16x16x32_bf16(kf2, qf[qi][2], sc[qi][ct], 0, 0, 0);
            }
        }
        __builtin_amdgcn_s_setprio(0);
#pragma unroll
        for (int qi = 0; qi < 2; ++qi) {
            const int qt = qi;
            float mx = sc[qi][0][0];
#pragma unroll
            for (int ct = 0; ct < 4; ++ct)
#pragma unroll
                for (int r = 0; r < 4; ++r)
                    mx = fmaxf(mx, sc[qi][ct][r]);
            mx = fmaxf(mx, __shfl_xor(mx, 16, 64));
            mx = fmaxf(mx, __shfl_xor(mx, 32, 64));
            // exact defer: if no lane's max grew, keep m_run (P <= 1 still holds)
            bool grow = !__all(mx <= m_run[qt]);
            float al = 1.0f;
            if (grow) {
                float mn = fmaxf(m_run[qt], mx);
                al = __builtin_amdgcn_exp2f(m_run[qt] - mn);
                m_run[qt] = mn;
            }
            grew[qi] = grow;
            float rs = 0.f;
            ushort_t pb[16];
#pragma unroll
            for (int ct = 0; ct < 4; ++ct)
#pragma unroll
                for (int r = 0; r < 4; ++r) {
                    float p = __builtin_amdgcn_exp2f(sc[qi][ct][r] - m_run[qt]);
                    rs += p;
                    pb[ct*4 + r] = f2bf(p);
                }
            rs += __shfl_xor(rs, 16, 64);
            rs += __shfl_xor(rs, 32, 64);
            l_run[qt] = l_run[qt] * al + rs;
            al2[qt] = al;
            const int pbase = ((w*2 + qt)*16 + ln) * 64;
#pragma unroll
            for (int ct = 0; ct < 4; ++ct) {
                ushort4 pk;
                pk.x = pb[ct*4+0]; pk.y = pb[ct*4+1]; pk.z = pb[ct*4+2]; pk.w = pb[ct*4+3];
                *(ushort4*)&p_s[pbase + ((ct*16 + g*4) ^ swzp)] = pk;
            }
        }

        // rescale O by exp2(m_old - m_new) only when some row's max grew
        if (grew[0] || grew[1]) {
#pragma unroll
            for (int qt = 0; qt < 2; ++qt)
#pragma unroll
                for (int r = 0; r < 4; ++r) {
                    float a = __shfl(al2[qt], g*4 + r, 16);
#pragma unroll
                    for (int dt = 0; dt < 6; ++dt)
                        acc_o[qt][dt][r] *= a;
                }
        }

        // V(kt) landed (3 K-prefetch remain in flight); cross-wave visibility
        asm volatile("s_waitcnt vmcnt(3)" ::: "memory");
        __builtin_amdgcn_s_barrier();
        __builtin_amdgcn_sched_barrier(0);
        asm volatile("s_waitcnt lgkmcnt(0)" ::: "memory");   // own P-writes complete
        __builtin_amdgcn_sched_barrier(0);

        // PV: pf per qt; vf shared across both qt
        __builtin_amdgcn_s_setprio(1);
#pragma unroll
        for (int kb = 0; kb < 2; ++kb) {
            bf16x8 pf2[2];
#pragma unroll
            for (int qt = 0; qt < 2; ++qt)
                pf2[qt] = *(const bf16x8*)&p_s[((w*2 + qt)*16 + ln)*64 + ((kb*32 + g*8) ^ swzp)];
#pragma unroll
            for (int dt = 0; dt < 6; ++dt) {
                bf16x8 vf = *(const bf16x8*)&v_s[((kb*4 + g)*96 + dt*16 + ln) * 8];
#pragma unroll
                for (int qt = 0; qt < 2; ++qt)
                    acc_o[qt][dt] = __builtin_amdgcn_mfma_f32_16x16x32_bf16(pf2[qt], vf, acc_o[qt][dt], 0, 0, 0);
            }
        }
        __builtin_amdgcn_s_setprio(0);

        __syncthreads();          // drains vmcnt: next K resident; all waves done with v_s/k_s[cur]
        if (kt < 15) stageV(kt + 1);
        cur ^= 1;
    }

    // epilogue: O/l, reverse-sparse scatter into ATT [4096][2304] bf16
#pragma unroll
    for (int qt = 0; qt < 2; ++qt) {
        float inv = 1.0f / l_run[qt];
#pragma unroll
        for (int r = 0; r < 4; ++r) {
            float iv = __shfl(inv, g*4 + r, 16);
            int gq = qb0 + w*32 + qt*16 + g*4 + r;
            size_t base = ((size_t)(gq * 4 + n_idx)) * DIM + h * DH;
#pragma unroll
            for (int dt = 0; dt < 6; ++dt)
                ATT[base + dt*16 + ln] = f2bf(acc_o[qt][dt][r] * iv);
        }
    }
}

// ---------------- launch ----------------
extern "C" void kernel_launch(void* const* d_in, const int* in_sizes, int n_in,
                              void* d_out, int out_size, void* d_ws, size_t ws_size,
                              hipStream_t stream) {
    const float* hidden = (const float*)d_in[0];
    const float* wq = (const float*)d_in[1];
    const float* bq = (const float*)d_in[2];
    const float* wk = (const float*)d_in[3];
    const float* bk = (const float*)d_in[4];
    const float* wv = (const float*)d_in[5];
    const float* bv = (const float*)d_in[6];
    const float* wo = (const float*)d_in[7];
    const float* bo = (const float*)d_in[8];
    float* out = (float*)d_out;

    char* ws = (char*)d_ws;
    ushort_t* Xb  = (ushort_t*)ws;                       // 4096x2304 bf16
    ushort_t* WTq = (ushort_t*)(ws + 18874368);          // [wq|wk|wv|wo]^T rows concat
    ushort_t* WTk = WTq + (size_t)DIM * DIM;
    ushort_t* WTv = WTk + (size_t)DIM * DIM;
    ushort_t* WTo = WTv + (size_t)DIM * DIM;
    ushort_t* Qb  = WTo + (size_t)DIM * DIM;             // [4][24][1024][96]
    ushort_t* Kb  = Qb + (size_t)S_TOK * DIM;            // [4][24][1024][96]
    ushort_t* Vtb = Kb + (size_t)S_TOK * DIM;            // [4][24][96][1024]  (V^T)
    ushort_t* ATT = Vtb + (size_t)S_TOK * DIM;           // [4096][2304] bf16

    // cast + all 4 weight transposes in ONE launch (z: 0-3 = W_z, 4 = cast)
    prep_kernel<<<dim3(72, 72, 5), 256, 0, stream>>>(hidden, wq, wk, wv, wo, WTq, Xb, DIM);

    // fused QKV projection: N = 3*2304 = 6912 -> grid (27,16) = 432 blocks
    gemm256<false><<<dim3(27, 16), 512, 0, stream>>>(Xb, WTq, bq, bk, bv, Qb, Kb, Vtb, nullptr);

    attn_kernel<<<dim3(768), 256, 0, stream>>>(Qb, Kb, Vtb, ATT);

    // output projection: N = 2304 -> 128^2 tiles, grid (18,32) = 576 blocks
    gemm128<<<dim3(18, 32), 256, 0, stream>>>(ATT, WTo, bo, out);
}